// Round 1
// baseline (375.940 us; speedup 1.0000x reference)
//
#include <hip/hip_runtime.h>

// MHA forward: x[2,4096,768] -> out[2,4096,768], 8 heads, head_dim 96.
// Strategy: bf16 MFMA GEMMs (fp32 accum) + flash attention.

typedef __bf16 bf16;
typedef __attribute__((ext_vector_type(4))) float f32x4;
typedef __attribute__((ext_vector_type(8))) __bf16 bf16x8;
typedef __attribute__((ext_vector_type(4))) __bf16 bf16x4;

#define EMB 768
#define SEQ 4096
#define NB 2
#define NHEADS 8
#define HD 96
#define BHTOT (NB * NHEADS)     // 16
#define MTOT (NB * SEQ)         // 8192
#define SCALE_F 0.10206207261596575f  // 96^-0.5

// ---------------- fp32 -> bf16 cast (vectorized, exact grid) ----------------
__global__ __launch_bounds__(256) void cast_f32_bf16(const float* __restrict__ in,
                                                     bf16* __restrict__ out) {
  const int i = (blockIdx.x * 256 + threadIdx.x) * 4;
  const f32x4 v = *reinterpret_cast<const f32x4*>(in + i);
  bf16x4 o;
  o[0] = (bf16)v[0]; o[1] = (bf16)v[1]; o[2] = (bf16)v[2]; o[3] = (bf16)v[3];
  *reinterpret_cast<bf16x4*>(out + i) = o;
}

// ---------------- GEMM: C[M,768] = A[M,768] * B[768,768]^T + bias ----------
// 128x128 block tile, 4 waves (each 64x64), BK=32, global_load_lds staging.
// MODE 0: write bf16 to head-split layout [bh][n][96].
// MODE 1: write fp32 row-major [m][768] (final output).
template <int MODE>
__global__ __launch_bounds__(256) void gemm_bt(const bf16* __restrict__ A,
                                               const bf16* __restrict__ B,
                                               const float* __restrict__ bias,
                                               void* __restrict__ out) {
  constexpr int K = EMB;
  __shared__ bf16 As[128 * 32];
  __shared__ bf16 Bs[128 * 32];
  const int tid = threadIdx.x;
  const int lane = tid & 63;
  const int wid = tid >> 6;
  const int wr = wid >> 1, wc = wid & 1;
  const int l15 = lane & 15, l4 = lane >> 4;
  const int rowBase = blockIdx.y * 128;
  const int colBase = blockIdx.x * 128;

  f32x4 acc[4][4] = {};

  for (int kt = 0; kt < K / 32; ++kt) {
    const int kb = kt * 32;
    // Stage A/B tiles: 128x32 bf16 each. chunk c (16B) -> row c/4, k-chunk c%4.
#pragma unroll
    for (int i = 0; i < 2; ++i) {
      const int c = (wid * 2 + i) * 64 + lane;
      const int row = c >> 2, cc = c & 3;
      const bf16* ga = A + (size_t)(rowBase + row) * K + kb + cc * 8;
      const bf16* gb = B + (size_t)(colBase + row) * K + kb + cc * 8;
      __builtin_amdgcn_global_load_lds(
          (const __attribute__((address_space(1))) void*)ga,
          (__attribute__((address_space(3))) void*)(As + (size_t)(wid * 2 + i) * 512),
          16, 0, 0);
      __builtin_amdgcn_global_load_lds(
          (const __attribute__((address_space(1))) void*)gb,
          (__attribute__((address_space(3))) void*)(Bs + (size_t)(wid * 2 + i) * 512),
          16, 0, 0);
    }
    __syncthreads();
    bf16x8 af[4], bfr[4];
#pragma unroll
    for (int t = 0; t < 4; ++t) {
      af[t]  = *reinterpret_cast<const bf16x8*>(As + (wr * 64 + t * 16 + l15) * 32 + l4 * 8);
      bfr[t] = *reinterpret_cast<const bf16x8*>(Bs + (wc * 64 + t * 16 + l15) * 32 + l4 * 8);
    }
#pragma unroll
    for (int mt = 0; mt < 4; ++mt)
#pragma unroll
      for (int nt = 0; nt < 4; ++nt)
        acc[mt][nt] = __builtin_amdgcn_mfma_f32_16x16x32_bf16(af[mt], bfr[nt], acc[mt][nt], 0, 0, 0);
    __syncthreads();
  }

  // Epilogue. D frag: col = lane&15 (n), row = (lane>>4)*4 + r (m).
#pragma unroll
  for (int mt = 0; mt < 4; ++mt) {
#pragma unroll
    for (int nt = 0; nt < 4; ++nt) {
      const int gn = colBase + wc * 64 + nt * 16 + l15;
      const float bv = bias[gn];
#pragma unroll
      for (int r = 0; r < 4; ++r) {
        const int gm = rowBase + wr * 64 + mt * 16 + l4 * 4 + r;
        const float v = acc[mt][nt][r] + bv;
        if (MODE == 0) {
          const int b = gm >> 12, n = gm & (SEQ - 1);
          const int h = gn / HD, d = gn - h * HD;
          ((bf16*)out)[((size_t)(b * NHEADS + h) * SEQ + n) * HD + d] = (bf16)v;
        } else {
          ((float*)out)[(size_t)gm * EMB + gn] = v;
        }
      }
    }
  }
}

// ---------------- V transpose: [bh][n][96] -> [bh][96][n] ----------------
__global__ __launch_bounds__(256) void transpose_v(const bf16* __restrict__ v,
                                                   bf16* __restrict__ vt) {
  __shared__ bf16 T[96][72];  // pad 64->72 to break bank conflicts
  const int bh = blockIdx.y;
  const int n0 = blockIdx.x * 64;
  const int tid = threadIdx.x;
#pragma unroll
  for (int i = 0; i < 3; ++i) {
    const int c = i * 256 + tid;          // 768 chunks of 8 bf16 (64 rows x 12)
    const int n = c / 12, cc = c % 12;
    const bf16x8 val = *reinterpret_cast<const bf16x8*>(
        v + ((size_t)bh * SEQ + n0 + n) * HD + cc * 8);
#pragma unroll
    for (int j = 0; j < 8; ++j) T[cc * 8 + j][n] = val[j];
  }
  __syncthreads();
#pragma unroll
  for (int i = 0; i < 3; ++i) {
    const int c = i * 256 + tid;          // 768 chunks (96 rows x 8)
    const int d = c >> 3, nc = c & 7;
    const bf16x8 val = *reinterpret_cast<const bf16x8*>(&T[d][nc * 8]);
    *reinterpret_cast<bf16x8*>(vt + ((size_t)bh * HD + d) * SEQ + n0 + nc * 8) = val;
  }
}

// ---------------- Flash attention ----------------
// Block = (bh, 128 q rows), 4 waves x 32 q rows. KV tile = 64.
__global__ __launch_bounds__(256) void attn_fwd(const bf16* __restrict__ q,
                                                const bf16* __restrict__ k,
                                                const bf16* __restrict__ vt,
                                                bf16* __restrict__ o) {
  __shared__ bf16 Ks[64][104];   // K tile  [ki][d],  pad 96->104
  __shared__ bf16 Vts[96][72];   // Vt tile [d][ki],  pad 64->72
  __shared__ bf16 Ps[4][32][72]; // per-wave P tile [q][ki], pad 64->72
  const int tid = threadIdx.x;
  const int lane = tid & 63;
  const int wid = tid >> 6;
  const int l15 = lane & 15, l4 = lane >> 4;
  const int bh = blockIdx.y;
  const int qbase = blockIdx.x * 128;
  const size_t head = (size_t)bh * SEQ * HD;

  // Q fragments in registers: 2 row-tiles x 3 k-chunks of 32.
  bf16x8 qf[2][3];
#pragma unroll
  for (int qr = 0; qr < 2; ++qr)
#pragma unroll
    for (int kc = 0; kc < 3; ++kc)
      qf[qr][kc] = *reinterpret_cast<const bf16x8*>(
          q + head + (size_t)(qbase + wid * 32 + qr * 16 + l15) * HD + kc * 32 + l4 * 8);

  f32x4 oacc[2][6] = {};
  float mrun[2][4], lrun[2][4];
#pragma unroll
  for (int qr = 0; qr < 2; ++qr)
#pragma unroll
    for (int r = 0; r < 4; ++r) { mrun[qr][r] = -1e30f; lrun[qr][r] = 0.f; }

  for (int kt = 0; kt < SEQ / 64; ++kt) {
    const int kv0 = kt * 64;
    // ---- stage K tile: 64x96 (768 chunks of 8 bf16) ----
#pragma unroll
    for (int i = 0; i < 3; ++i) {
      const int c = i * 256 + tid;
      const int row = c / 12, cc = c % 12;
      const bf16x8 val = *reinterpret_cast<const bf16x8*>(
          k + head + (size_t)(kv0 + row) * HD + cc * 8);
      *reinterpret_cast<bf16x8*>(&Ks[row][cc * 8]) = val;
    }
    // ---- stage Vt tile: 96x64 (768 chunks) ----
#pragma unroll
    for (int i = 0; i < 3; ++i) {
      const int c = i * 256 + tid;
      const int row = c >> 3, cc = c & 7;
      const bf16x8 val = *reinterpret_cast<const bf16x8*>(
          vt + (size_t)bh * HD * SEQ + (size_t)row * SEQ + kv0 + cc * 8);
      *reinterpret_cast<bf16x8*>(&Vts[row][cc * 8]) = val;
    }
    __syncthreads();

    // ---- S = Q K^T (scaled later). sacc[qr][kc]: D col=ki, row=q ----
    f32x4 sacc[2][4] = {};
#pragma unroll
    for (int kc = 0; kc < 4; ++kc) {
#pragma unroll
      for (int kch = 0; kch < 3; ++kch) {
        const bf16x8 kf = *reinterpret_cast<const bf16x8*>(&Ks[kc * 16 + l15][kch * 32 + l4 * 8]);
        sacc[0][kc] = __builtin_amdgcn_mfma_f32_16x16x32_bf16(qf[0][kch], kf, sacc[0][kc], 0, 0, 0);
        sacc[1][kc] = __builtin_amdgcn_mfma_f32_16x16x32_bf16(qf[1][kch], kf, sacc[1][kc], 0, 0, 0);
      }
    }

    // ---- online softmax (rows in regs, 16 cols across lanes) ----
#pragma unroll
    for (int qr = 0; qr < 2; ++qr) {
      float pj[4][4];
      float rmax[4];
#pragma unroll
      for (int r = 0; r < 4; ++r) {
        float mx = -1e30f;
#pragma unroll
        for (int kc = 0; kc < 4; ++kc) {
          const float sv = sacc[qr][kc][r] * SCALE_F;
          pj[kc][r] = sv;
          mx = fmaxf(mx, sv);
        }
        rmax[r] = mx;
      }
#pragma unroll
      for (int msk = 1; msk < 16; msk <<= 1)
#pragma unroll
        for (int r = 0; r < 4; ++r)
          rmax[r] = fmaxf(rmax[r], __shfl_xor(rmax[r], msk, 64));
      float rsum[4];
#pragma unroll
      for (int r = 0; r < 4; ++r) {
        const float mnew = fmaxf(mrun[qr][r], rmax[r]);
        const float fac = __expf(mrun[qr][r] - mnew);
        mrun[qr][r] = mnew;
        float s = 0.f;
#pragma unroll
        for (int kc = 0; kc < 4; ++kc) {
          const float e = __expf(pj[kc][r] - mnew);
          pj[kc][r] = e;
          s += e;
        }
        rsum[r] = s;
        lrun[qr][r] *= fac;
#pragma unroll
        for (int dc = 0; dc < 6; ++dc) oacc[qr][dc][r] *= fac;
      }
#pragma unroll
      for (int msk = 1; msk < 16; msk <<= 1)
#pragma unroll
        for (int r = 0; r < 4; ++r)
          rsum[r] += __shfl_xor(rsum[r], msk, 64);
#pragma unroll
      for (int r = 0; r < 4; ++r) lrun[qr][r] += rsum[r];
      // write P tile (D-frag layout -> LDS rows) for A-frag reload
#pragma unroll
      for (int kc = 0; kc < 4; ++kc)
#pragma unroll
        for (int r = 0; r < 4; ++r)
          Ps[wid][qr * 16 + l4 * 4 + r][kc * 16 + l15] = (bf16)pj[kc][r];
    }
    asm volatile("s_waitcnt lgkmcnt(0)" ::: "memory");  // wave-local P visibility

    // ---- O += P * Vt^T ----
#pragma unroll
    for (int kch = 0; kch < 2; ++kch) {
      const bf16x8 pf0 = *reinterpret_cast<const bf16x8*>(&Ps[wid][0 * 16 + l15][kch * 32 + l4 * 8]);
      const bf16x8 pf1 = *reinterpret_cast<const bf16x8*>(&Ps[wid][1 * 16 + l15][kch * 32 + l4 * 8]);
#pragma unroll
      for (int dc = 0; dc < 6; ++dc) {
        const bf16x8 vf = *reinterpret_cast<const bf16x8*>(&Vts[dc * 16 + l15][kch * 32 + l4 * 8]);
        oacc[0][dc] = __builtin_amdgcn_mfma_f32_16x16x32_bf16(pf0, vf, oacc[0][dc], 0, 0, 0);
        oacc[1][dc] = __builtin_amdgcn_mfma_f32_16x16x32_bf16(pf1, vf, oacc[1][dc], 0, 0, 0);
      }
    }
    __syncthreads();
  }

  // ---- normalize + write attn output to [m][768] bf16 (m = b*4096+n) ----
  const int b = bh >> 3, h = bh & 7;
#pragma unroll
  for (int qr = 0; qr < 2; ++qr)
#pragma unroll
    for (int r = 0; r < 4; ++r) {
      const float inv = 1.f / lrun[qr][r];
      const int n = qbase + wid * 32 + qr * 16 + l4 * 4 + r;
#pragma unroll
      for (int dc = 0; dc < 6; ++dc) {
        const int d = dc * 16 + l15;
        o[((size_t)(b * SEQ + n)) * EMB + h * HD + d] = (bf16)(oacc[qr][dc][r] * inv);
      }
    }
}

// ---------------- launch ----------------
extern "C" void kernel_launch(void* const* d_in, const int* in_sizes, int n_in,
                              void* d_out, int out_size, void* d_ws, size_t ws_size,
                              hipStream_t stream) {
  const float* x  = (const float*)d_in[0];
  const float* Wq = (const float*)d_in[1];
  const float* bq = (const float*)d_in[2];
  const float* Wk = (const float*)d_in[3];
  const float* bk = (const float*)d_in[4];
  const float* Wv = (const float*)d_in[5];
  const float* bv = (const float*)d_in[6];
  const float* Wo = (const float*)d_in[7];
  const float* bo = (const float*)d_in[8];

  const size_t XN = (size_t)MTOT * EMB;  // 6291456
  const size_t WN = (size_t)EMB * EMB;   // 589824

  bf16* p = (bf16*)d_ws;
  bf16* xbf = p; p += XN;
  bf16* wqb = p; p += WN;
  bf16* wkb = p; p += WN;
  bf16* wvb = p; p += WN;
  bf16* wob = p; p += WN;
  bf16* qb  = p; p += XN;
  bf16* kb  = p; p += XN;
  bf16* vb  = p; p += XN;
  bf16* vtb = p; p += XN;
  bf16* ao  = p; p += XN;
  // total ws use: (6*XN + 4*WN)*2 bytes ~= 80.2 MB

  cast_f32_bf16<<<XN / 1024, 256, 0, stream>>>(x,  xbf);
  cast_f32_bf16<<<WN / 1024, 256, 0, stream>>>(Wq, wqb);
  cast_f32_bf16<<<WN / 1024, 256, 0, stream>>>(Wk, wkb);
  cast_f32_bf16<<<WN / 1024, 256, 0, stream>>>(Wv, wvb);
  cast_f32_bf16<<<WN / 1024, 256, 0, stream>>>(Wo, wob);

  const dim3 gg(EMB / 128, MTOT / 128);  // (6, 64)
  gemm_bt<0><<<gg, 256, 0, stream>>>(xbf, wqb, bq, qb);
  gemm_bt<0><<<gg, 256, 0, stream>>>(xbf, wkb, bk, kb);
  gemm_bt<0><<<gg, 256, 0, stream>>>(xbf, wvb, bv, vb);

  transpose_v<<<dim3(SEQ / 64, BHTOT), 256, 0, stream>>>(vb, vtb);
  attn_fwd<<<dim3(SEQ / 128, BHTOT), 256, 0, stream>>>(qb, kb, vtb, ao);

  gemm_bt<1><<<gg, 256, 0, stream>>>(ao, wob, bo, d_out);
}

// Round 2
// 301.858 us; speedup vs baseline: 1.2454x; 1.2454x over previous
//
#include <hip/hip_runtime.h>

// MHA forward: x[2,4096,768] -> out[2,4096,768], 8 heads, head_dim 96.
// bf16 MFMA GEMMs (fp32 accum) + flash attention (swapped-QK^T, in-register
// softmax/P-transmute, double-buffered K/V staging).

typedef __bf16 bf16;
typedef __attribute__((ext_vector_type(4))) float f32x4;
typedef __attribute__((ext_vector_type(8))) __bf16 bf16x8;
typedef __attribute__((ext_vector_type(4))) __bf16 bf16x4;

#define EMB 768
#define SEQ 4096
#define NB 2
#define NHEADS 8
#define HD 96
#define BHTOT (NB * NHEADS)     // 16
#define MTOT (NB * SEQ)         // 8192
#define SCALE_F 0.10206207261596575f  // 96^-0.5

// ---------------- fp32 -> bf16 cast ----------------
__global__ __launch_bounds__(256) void cast_f32_bf16(const float* __restrict__ in,
                                                     bf16* __restrict__ out) {
  const int i = (blockIdx.x * 256 + threadIdx.x) * 4;
  const f32x4 v = *reinterpret_cast<const f32x4*>(in + i);
  bf16x4 o;
  o[0] = (bf16)v[0]; o[1] = (bf16)v[1]; o[2] = (bf16)v[2]; o[3] = (bf16)v[3];
  *reinterpret_cast<bf16x4*>(out + i) = o;
}

// ---------------- GEMM: C[M,768] = A[M,768] * B[768,768]^T + bias ----------
template <int MODE>
__global__ __launch_bounds__(256) void gemm_bt(const bf16* __restrict__ A,
                                               const bf16* __restrict__ B,
                                               const float* __restrict__ bias,
                                               void* __restrict__ out) {
  constexpr int K = EMB;
  __shared__ bf16 As[128 * 32];
  __shared__ bf16 Bs[128 * 32];
  const int tid = threadIdx.x;
  const int lane = tid & 63;
  const int wid = tid >> 6;
  const int wr = wid >> 1, wc = wid & 1;
  const int l15 = lane & 15, l4 = lane >> 4;
  const int rowBase = blockIdx.y * 128;
  const int colBase = blockIdx.x * 128;

  f32x4 acc[4][4] = {};

  for (int kt = 0; kt < K / 32; ++kt) {
    const int kb = kt * 32;
#pragma unroll
    for (int i = 0; i < 2; ++i) {
      const int c = (wid * 2 + i) * 64 + lane;
      const int row = c >> 2, cc = c & 3;
      const bf16* ga = A + (size_t)(rowBase + row) * K + kb + cc * 8;
      const bf16* gb = B + (size_t)(colBase + row) * K + kb + cc * 8;
      __builtin_amdgcn_global_load_lds(
          (const __attribute__((address_space(1))) void*)ga,
          (__attribute__((address_space(3))) void*)(As + (size_t)(wid * 2 + i) * 512),
          16, 0, 0);
      __builtin_amdgcn_global_load_lds(
          (const __attribute__((address_space(1))) void*)gb,
          (__attribute__((address_space(3))) void*)(Bs + (size_t)(wid * 2 + i) * 512),
          16, 0, 0);
    }
    __syncthreads();
    bf16x8 af[4], bfr[4];
#pragma unroll
    for (int t = 0; t < 4; ++t) {
      af[t]  = *reinterpret_cast<const bf16x8*>(As + (wr * 64 + t * 16 + l15) * 32 + l4 * 8);
      bfr[t] = *reinterpret_cast<const bf16x8*>(Bs + (wc * 64 + t * 16 + l15) * 32 + l4 * 8);
    }
#pragma unroll
    for (int mt = 0; mt < 4; ++mt)
#pragma unroll
      for (int nt = 0; nt < 4; ++nt)
        acc[mt][nt] = __builtin_amdgcn_mfma_f32_16x16x32_bf16(af[mt], bfr[nt], acc[mt][nt], 0, 0, 0);
    __syncthreads();
  }

#pragma unroll
  for (int mt = 0; mt < 4; ++mt) {
#pragma unroll
    for (int nt = 0; nt < 4; ++nt) {
      const int gn = colBase + wc * 64 + nt * 16 + l15;
      const float bv = bias[gn];
#pragma unroll
      for (int r = 0; r < 4; ++r) {
        const int gm = rowBase + wr * 64 + mt * 16 + l4 * 4 + r;
        const float v = acc[mt][nt][r] + bv;
        if (MODE == 0) {
          const int b = gm >> 12, n = gm & (SEQ - 1);
          const int h = gn / HD, d = gn - h * HD;
          ((bf16*)out)[((size_t)(b * NHEADS + h) * SEQ + n) * HD + d] = (bf16)v;
        } else {
          ((float*)out)[(size_t)gm * EMB + gn] = v;
        }
      }
    }
  }
}

// ---------------- V transpose: [bh][n][96] -> [bh][96][n] ----------------
__global__ __launch_bounds__(256) void transpose_v(const bf16* __restrict__ v,
                                                   bf16* __restrict__ vt) {
  __shared__ bf16 T[96][72];
  const int bh = blockIdx.y;
  const int n0 = blockIdx.x * 64;
  const int tid = threadIdx.x;
#pragma unroll
  for (int i = 0; i < 3; ++i) {
    const int c = i * 256 + tid;
    const int n = c / 12, cc = c % 12;
    const bf16x8 val = *reinterpret_cast<const bf16x8*>(
        v + ((size_t)bh * SEQ + n0 + n) * HD + cc * 8);
#pragma unroll
    for (int j = 0; j < 8; ++j) T[cc * 8 + j][n] = val[j];
  }
  __syncthreads();
#pragma unroll
  for (int i = 0; i < 3; ++i) {
    const int c = i * 256 + tid;
    const int d = c >> 3, nc = c & 7;
    const bf16x8 val = *reinterpret_cast<const bf16x8*>(&T[d][nc * 8]);
    *reinterpret_cast<bf16x8*>(vt + ((size_t)bh * HD + d) * SEQ + n0 + nc * 8) = val;
  }
}

// ---------------- Flash attention ----------------
// Block = (bh, 128 q rows), 8 waves x 16 q rows, 512 threads. KV tile = 64,
// double-buffered. S^T = mfma(K,Q): lane(l4,l15) reg r of block kc holds
// S^T[ki=kc*16+l4*4+r][q=q0+l15]. P re-laid to PV A-frag via cvt_pk+bpermute.
__global__ __launch_bounds__(512, 4) void attn_fwd(const bf16* __restrict__ q,
                                                   const bf16* __restrict__ k,
                                                   const bf16* __restrict__ vt,
                                                   bf16* __restrict__ o) {
  __shared__ bf16 Ks[2][64][104];   // pad 96->104 (stride 20 banks)
  __shared__ bf16 Vts[2][96][72];   // pad 64->72
  const int tid = threadIdx.x;      // 0..511
  const int lane = tid & 63;
  const int wid = tid >> 6;         // 0..7
  const int l15 = lane & 15, l4 = lane >> 4;
  const int bh = blockIdx.y;
  const int q0 = blockIdx.x * 128 + wid * 16;
  const size_t head = (size_t)bh * SEQ * HD;
  const bf16* kg = k + head;
  const bf16* vg = vt + (size_t)bh * (size_t)HD * SEQ;

  // staging chunk coords (chunk = 8 bf16 = 16B); 768 chunks over 512 threads
  const int kr0 = tid / 12, kc0 = tid % 12;
  const int t2 = 512 + tid;
  const int kr1 = t2 / 12, kc1 = t2 % 12;
  const int vr0 = tid >> 3, vc0 = tid & 7;
  const int vr1 = 64 + (tid >> 3);
  const bool low = (tid < 256);     // wave-uniform (waves 0..3)

  // Q fragments (B-frag): lane holds Q[q0+l15][kch*32 + l4*8 + j]
  bf16x8 qf[3];
#pragma unroll
  for (int kch = 0; kch < 3; ++kch)
    qf[kch] = *reinterpret_cast<const bf16x8*>(
        q + head + (size_t)(q0 + l15) * HD + kch * 32 + l4 * 8);

  f32x4 oacc[6] = {};
  float mrun = -1e30f, lrun = 0.f;  // state for q = q0 + l15 (replicated over l4)

  bf16x8 rk0, rk1, rv0, rv1;
  // prologue: stage tile 0
  rk0 = *reinterpret_cast<const bf16x8*>(kg + (size_t)kr0 * HD + kc0 * 8);
  if (low) rk1 = *reinterpret_cast<const bf16x8*>(kg + (size_t)kr1 * HD + kc1 * 8);
  rv0 = *reinterpret_cast<const bf16x8*>(vg + (size_t)vr0 * SEQ + vc0 * 8);
  if (low) rv1 = *reinterpret_cast<const bf16x8*>(vg + (size_t)vr1 * SEQ + vc0 * 8);
  *reinterpret_cast<bf16x8*>(&Ks[0][kr0][kc0 * 8]) = rk0;
  if (low) *reinterpret_cast<bf16x8*>(&Ks[0][kr1][kc1 * 8]) = rk1;
  *reinterpret_cast<bf16x8*>(&Vts[0][vr0][vc0 * 8]) = rv0;
  if (low) *reinterpret_cast<bf16x8*>(&Vts[0][vr1][vc0 * 8]) = rv1;
  __syncthreads();

  for (int kt = 0; kt < SEQ / 64; ++kt) {
    const int cur = kt & 1;
    const bool pre = (kt < SEQ / 64 - 1);
    // issue next-tile global loads early (latency hides under compute)
    if (pre) {
      const int kv0 = (kt + 1) * 64;
      rk0 = *reinterpret_cast<const bf16x8*>(kg + (size_t)(kv0 + kr0) * HD + kc0 * 8);
      if (low) rk1 = *reinterpret_cast<const bf16x8*>(kg + (size_t)(kv0 + kr1) * HD + kc1 * 8);
      rv0 = *reinterpret_cast<const bf16x8*>(vg + (size_t)vr0 * SEQ + kv0 + vc0 * 8);
      if (low) rv1 = *reinterpret_cast<const bf16x8*>(vg + (size_t)vr1 * SEQ + kv0 + vc0 * 8);
    }

    // ---- S^T = K Q^T ----
    f32x4 sacc[4] = {};
#pragma unroll
    for (int kc = 0; kc < 4; ++kc) {
#pragma unroll
      for (int kch = 0; kch < 3; ++kch) {
        const bf16x8 kf = *reinterpret_cast<const bf16x8*>(&Ks[cur][kc * 16 + l15][kch * 32 + l4 * 8]);
        sacc[kc] = __builtin_amdgcn_mfma_f32_16x16x32_bf16(kf, qf[kch], sacc[kc], 0, 0, 0);
      }
    }

    // ---- online softmax (16 ki in-reg, reduce over l4 groups) ----
    float mx = -1e30f;
#pragma unroll
    for (int kc = 0; kc < 4; ++kc)
#pragma unroll
      for (int r = 0; r < 4; ++r) {
        const float sv = sacc[kc][r] * SCALE_F;
        sacc[kc][r] = sv;
        mx = fmaxf(mx, sv);
      }
    mx = fmaxf(mx, __shfl_xor(mx, 16, 64));
    mx = fmaxf(mx, __shfl_xor(mx, 32, 64));
    const float mnew = fmaxf(mrun, mx);
    const float fac = __expf(mrun - mnew);
    mrun = mnew;
    float sum = 0.f;
#pragma unroll
    for (int kc = 0; kc < 4; ++kc)
#pragma unroll
      for (int r = 0; r < 4; ++r) {
        const float e = __expf(sacc[kc][r] - mnew);
        sacc[kc][r] = e;
        sum += e;
      }
    sum += __shfl_xor(sum, 16, 64);
    sum += __shfl_xor(sum, 32, 64);
    lrun = lrun * fac + sum;

    // rescale O: row r of oacc is q_local = l4*4+r; fac lives at lane l15=q_local
    float facr[4];
#pragma unroll
    for (int r = 0; r < 4; ++r) facr[r] = __shfl(fac, l4 * 4 + r, 64);
#pragma unroll
    for (int dc = 0; dc < 6; ++dc)
#pragma unroll
      for (int r = 0; r < 4; ++r) oacc[dc][r] *= facr[r];

    // ---- transmute P (D-frag of S^T) -> A-frag bf16, in-register ----
    unsigned int pk[4][2];
#pragma unroll
    for (int kc = 0; kc < 4; ++kc)
#pragma unroll
      for (int h = 0; h < 2; ++h) {
        unsigned int r_;
        asm("v_cvt_pk_bf16_f32 %0, %1, %2"
            : "=v"(r_) : "v"(sacc[kc][2 * h]), "v"(sacc[kc][2 * h + 1]));
        pk[kc][h] = r_;
      }
    bf16x8 pf[2];
#pragma unroll
    for (int c = 0; c < 2; ++c) {
      unsigned int pd[4];
#pragma unroll
      for (int m = 0; m < 4; ++m) {
        const int sl = ((l4 & 1) * 2 + (m >> 1)) * 16 + l15;
        const unsigned int a = (unsigned int)__shfl((int)pk[c * 2][m & 1], sl, 64);
        const unsigned int b = (unsigned int)__shfl((int)pk[c * 2 + 1][m & 1], sl, 64);
        pd[m] = (l4 < 2) ? a : b;
      }
      pf[c] = *reinterpret_cast<bf16x8*>(pd);
    }

    // ---- O += P * V ----
#pragma unroll
    for (int c = 0; c < 2; ++c)
#pragma unroll
      for (int dc = 0; dc < 6; ++dc) {
        const bf16x8 vf = *reinterpret_cast<const bf16x8*>(&Vts[cur][dc * 16 + l15][c * 32 + l4 * 8]);
        oacc[dc] = __builtin_amdgcn_mfma_f32_16x16x32_bf16(pf[c], vf, oacc[dc], 0, 0, 0);
      }

    // write next tile to the other buffer (its readers are past the barrier)
    if (pre) {
      *reinterpret_cast<bf16x8*>(&Ks[cur ^ 1][kr0][kc0 * 8]) = rk0;
      if (low) *reinterpret_cast<bf16x8*>(&Ks[cur ^ 1][kr1][kc1 * 8]) = rk1;
      *reinterpret_cast<bf16x8*>(&Vts[cur ^ 1][vr0][vc0 * 8]) = rv0;
      if (low) *reinterpret_cast<bf16x8*>(&Vts[cur ^ 1][vr1][vc0 * 8]) = rv1;
    }
    __syncthreads();
  }

  // ---- normalize + write: O row q_local = l4*4+r, col d = dc*16+l15 ----
  const int b = bh >> 3, h = bh & 7;
  const float rlv = 1.f / lrun;
  float invr[4];
#pragma unroll
  for (int r = 0; r < 4; ++r) invr[r] = __shfl(rlv, l4 * 4 + r, 64);
#pragma unroll
  for (int r = 0; r < 4; ++r) {
    const int n = q0 + l4 * 4 + r;
#pragma unroll
    for (int dc = 0; dc < 6; ++dc) {
      const int d = dc * 16 + l15;
      o[((size_t)(b * SEQ + n)) * EMB + h * HD + d] = (bf16)(oacc[dc][r] * invr[r]);
    }
  }
}

// ---------------- launch ----------------
extern "C" void kernel_launch(void* const* d_in, const int* in_sizes, int n_in,
                              void* d_out, int out_size, void* d_ws, size_t ws_size,
                              hipStream_t stream) {
  const float* x  = (const float*)d_in[0];
  const float* Wq = (const float*)d_in[1];
  const float* bq = (const float*)d_in[2];
  const float* Wk = (const float*)d_in[3];
  const float* bk = (const float*)d_in[4];
  const float* Wv = (const float*)d_in[5];
  const float* bv = (const float*)d_in[6];
  const float* Wo = (const float*)d_in[7];
  const float* bo = (const float*)d_in[8];

  const size_t XN = (size_t)MTOT * EMB;
  const size_t WN = (size_t)EMB * EMB;

  bf16* p = (bf16*)d_ws;
  bf16* xbf = p; p += XN;
  bf16* wqb = p; p += WN;
  bf16* wkb = p; p += WN;
  bf16* wvb = p; p += WN;
  bf16* wob = p; p += WN;
  bf16* qb  = p; p += XN;
  bf16* kb  = p; p += XN;
  bf16* vb  = p; p += XN;
  bf16* vtb = p; p += XN;
  bf16* ao  = p; p += XN;

  cast_f32_bf16<<<XN / 1024, 256, 0, stream>>>(x,  xbf);
  cast_f32_bf16<<<WN / 1024, 256, 0, stream>>>(Wq, wqb);
  cast_f32_bf16<<<WN / 1024, 256, 0, stream>>>(Wk, wkb);
  cast_f32_bf16<<<WN / 1024, 256, 0, stream>>>(Wv, wvb);
  cast_f32_bf16<<<WN / 1024, 256, 0, stream>>>(Wo, wob);

  const dim3 gg(EMB / 128, MTOT / 128);
  gemm_bt<0><<<gg, 256, 0, stream>>>(xbf, wqb, bq, qb);
  gemm_bt<0><<<gg, 256, 0, stream>>>(xbf, wkb, bk, kb);
  gemm_bt<0><<<gg, 256, 0, stream>>>(xbf, wvb, bv, vb);

  transpose_v<<<dim3(SEQ / 64, BHTOT), 256, 0, stream>>>(vb, vtb);
  attn_fwd<<<dim3(SEQ / 128, BHTOT), 512, 0, stream>>>(qb, kb, vtb, ao);

  gemm_bt<1><<<gg, 256, 0, stream>>>(ao, wob, bo, d_out);
}

// Round 3
// 277.497 us; speedup vs baseline: 1.3548x; 1.0878x over previous
//
#include <hip/hip_runtime.h>

// MHA forward: x[2,4096,768] -> out[2,4096,768], 8 heads, head_dim 96.
// bf16 MFMA GEMMs (fp32 accum) + flash attention (swapped-QK^T, 32 q/wave,
// XOR-swizzled K/V LDS, exp2-domain softmax, defer-max, in-register P).

typedef __bf16 bf16;
typedef __attribute__((ext_vector_type(4))) float f32x4;
typedef __attribute__((ext_vector_type(8))) __bf16 bf16x8;
typedef __attribute__((ext_vector_type(4))) __bf16 bf16x4;

#define EMB 768
#define SEQ 4096
#define NB 2
#define NHEADS 8
#define HD 96
#define BHTOT (NB * NHEADS)     // 16
#define MTOT (NB * SEQ)         // 8192
// softmax scale folded into Q gemm epilogue, in exp2 domain:
#define QSCALE 0.14724241052735512f   // 96^-0.5 * log2(e)

// ---------------- fp32 -> bf16 cast (x) ----------------
__global__ __launch_bounds__(256) void cast_f32_bf16(const float* __restrict__ in,
                                                     bf16* __restrict__ out) {
  const int i = (blockIdx.x * 256 + threadIdx.x) * 4;
  const f32x4 v = *reinterpret_cast<const f32x4*>(in + i);
  bf16x4 o;
  o[0] = (bf16)v[0]; o[1] = (bf16)v[1]; o[2] = (bf16)v[2]; o[3] = (bf16)v[3];
  *reinterpret_cast<bf16x4*>(out + i) = o;
}

// ---------------- fused 4-weight cast ----------------
__global__ __launch_bounds__(256) void cast_w4(const float* __restrict__ w0,
                                               const float* __restrict__ w1,
                                               const float* __restrict__ w2,
                                               const float* __restrict__ w3,
                                               bf16* __restrict__ o0,
                                               bf16* __restrict__ o1,
                                               bf16* __restrict__ o2,
                                               bf16* __restrict__ o3) {
  const float* w = (blockIdx.y == 0) ? w0 : (blockIdx.y == 1) ? w1 : (blockIdx.y == 2) ? w2 : w3;
  bf16* o = (blockIdx.y == 0) ? o0 : (blockIdx.y == 1) ? o1 : (blockIdx.y == 2) ? o2 : o3;
  const int i = (blockIdx.x * 256 + threadIdx.x) * 4;
  const f32x4 v = *reinterpret_cast<const f32x4*>(w + i);
  bf16x4 ob;
  ob[0] = (bf16)v[0]; ob[1] = (bf16)v[1]; ob[2] = (bf16)v[2]; ob[3] = (bf16)v[3];
  *reinterpret_cast<bf16x4*>(o + i) = ob;
}

// ---------------- GEMM: C[M,768] = (A[M,768] * B[768,768]^T + bias)*oscale --
template <int MODE>
__global__ __launch_bounds__(256) void gemm_bt(const bf16* __restrict__ A,
                                               const bf16* __restrict__ B,
                                               const float* __restrict__ bias,
                                               void* __restrict__ out,
                                               float oscale) {
  constexpr int K = EMB;
  __shared__ bf16 As[128 * 32];
  __shared__ bf16 Bs[128 * 32];
  const int tid = threadIdx.x;
  const int lane = tid & 63;
  const int wid = tid >> 6;
  const int wr = wid >> 1, wc = wid & 1;
  const int l15 = lane & 15, l4 = lane >> 4;
  const int rowBase = blockIdx.y * 128;
  const int colBase = blockIdx.x * 128;

  f32x4 acc[4][4] = {};

  for (int kt = 0; kt < K / 32; ++kt) {
    const int kb = kt * 32;
#pragma unroll
    for (int i = 0; i < 2; ++i) {
      const int c = (wid * 2 + i) * 64 + lane;
      const int row = c >> 2, cc = c & 3;
      const bf16* ga = A + (size_t)(rowBase + row) * K + kb + cc * 8;
      const bf16* gb = B + (size_t)(colBase + row) * K + kb + cc * 8;
      __builtin_amdgcn_global_load_lds(
          (const __attribute__((address_space(1))) void*)ga,
          (__attribute__((address_space(3))) void*)(As + (size_t)(wid * 2 + i) * 512),
          16, 0, 0);
      __builtin_amdgcn_global_load_lds(
          (const __attribute__((address_space(1))) void*)gb,
          (__attribute__((address_space(3))) void*)(Bs + (size_t)(wid * 2 + i) * 512),
          16, 0, 0);
    }
    __syncthreads();
    bf16x8 af[4], bfr[4];
#pragma unroll
    for (int t = 0; t < 4; ++t) {
      af[t]  = *reinterpret_cast<const bf16x8*>(As + (wr * 64 + t * 16 + l15) * 32 + l4 * 8);
      bfr[t] = *reinterpret_cast<const bf16x8*>(Bs + (wc * 64 + t * 16 + l15) * 32 + l4 * 8);
    }
#pragma unroll
    for (int mt = 0; mt < 4; ++mt)
#pragma unroll
      for (int nt = 0; nt < 4; ++nt)
        acc[mt][nt] = __builtin_amdgcn_mfma_f32_16x16x32_bf16(af[mt], bfr[nt], acc[mt][nt], 0, 0, 0);
    __syncthreads();
  }

#pragma unroll
  for (int mt = 0; mt < 4; ++mt) {
#pragma unroll
    for (int nt = 0; nt < 4; ++nt) {
      const int gn = colBase + wc * 64 + nt * 16 + l15;
      const float bv = bias[gn];
#pragma unroll
      for (int r = 0; r < 4; ++r) {
        const int gm = rowBase + wr * 64 + mt * 16 + l4 * 4 + r;
        const float v = (acc[mt][nt][r] + bv) * oscale;
        if (MODE == 0) {
          const int b = gm >> 12, n = gm & (SEQ - 1);
          const int h = gn / HD, d = gn - h * HD;
          ((bf16*)out)[((size_t)(b * NHEADS + h) * SEQ + n) * HD + d] = (bf16)v;
        } else {
          ((float*)out)[(size_t)gm * EMB + gn] = v;
        }
      }
    }
  }
}

// ---------------- V transpose: [bh][n][96] -> [bh][96][n] ----------------
__global__ __launch_bounds__(256) void transpose_v(const bf16* __restrict__ v,
                                                   bf16* __restrict__ vt) {
  __shared__ bf16 T[96][72];
  const int bh = blockIdx.y;
  const int n0 = blockIdx.x * 64;
  const int tid = threadIdx.x;
#pragma unroll
  for (int i = 0; i < 3; ++i) {
    const int c = i * 256 + tid;
    const int n = c / 12, cc = c % 12;
    const bf16x8 val = *reinterpret_cast<const bf16x8*>(
        v + ((size_t)bh * SEQ + n0 + n) * HD + cc * 8);
#pragma unroll
    for (int j = 0; j < 8; ++j) T[cc * 8 + j][n] = val[j];
  }
  __syncthreads();
#pragma unroll
  for (int i = 0; i < 3; ++i) {
    const int c = i * 256 + tid;
    const int d = c >> 3, nc = c & 7;
    const bf16x8 val = *reinterpret_cast<const bf16x8*>(&T[d][nc * 8]);
    *reinterpret_cast<bf16x8*>(vt + ((size_t)bh * HD + d) * SEQ + n0 + nc * 8) = val;
  }
}

// ---------------- Flash attention ----------------
// Block = (bh, 128 q rows), 4 waves x 32 q (two 16-q groups), 256 threads.
// KV tile 64, double-buffered, XOR-swizzled LDS. S^T = mfma(K,Q); softmax in
// exp2 domain with defer-max; P -> A-frag via cvt_pk + shuffles in-register.
__global__ __launch_bounds__(256, 2) void attn_fwd(const bf16* __restrict__ q,
                                                   const bf16* __restrict__ k,
                                                   const bf16* __restrict__ vt,
                                                   bf16* __restrict__ o) {
  __shared__ bf16 Ks[2][64 * 128];   // row stride 128 (256B), slot ^= row&7
  __shared__ bf16 Vts[2][96 * 64];   // row stride 64 (128B),  slot ^= row&7
  const int tid = threadIdx.x;       // 0..255
  const int lane = tid & 63;
  const int wid = tid >> 6;          // 0..3
  const int l15 = lane & 15, l4 = lane >> 4;
  const int bh = blockIdx.y;
  const int q0 = blockIdx.x * 128 + wid * 32;
  const size_t head = (size_t)bh * SEQ * HD;
  const bf16* kg = k + head;
  const bf16* vg = vt + (size_t)bh * (size_t)HD * SEQ;

  // staging coords: 768 16B-chunks each for K (64x12) and Vt (96x8)
  int kws[3], vws[3];
  const bf16* kgp[3];
  const bf16* vgp[3];
  const int vc = tid & 7;
#pragma unroll
  for (int i = 0; i < 3; ++i) {
    const int c = i * 256 + tid;
    const int kr = c / 12, kcc = c % 12;
    kws[i] = kr * 128 + ((kcc ^ (kr & 7)) * 8);
    kgp[i] = kg + (size_t)kr * HD + kcc * 8;
    const int vr = i * 32 + (tid >> 3);
    vws[i] = vr * 64 + ((vc ^ (vr & 7)) * 8);
    vgp[i] = vg + (size_t)vr * SEQ + vc * 8;
  }

  // Q fragments (B-frag) for both q-groups; scale already folded into q.
  bf16x8 qf[2][3];
#pragma unroll
  for (int g = 0; g < 2; ++g)
#pragma unroll
    for (int kch = 0; kch < 3; ++kch)
      qf[g][kch] = *reinterpret_cast<const bf16x8*>(
          q + head + (size_t)(q0 + g * 16 + l15) * HD + kch * 32 + l4 * 8);

  f32x4 oacc[2][6] = {};
  float mrun[2] = {-1e30f, -1e30f}, lrun[2] = {0.f, 0.f};

  // prologue: stage tile 0
#pragma unroll
  for (int i = 0; i < 3; ++i) {
    *reinterpret_cast<bf16x8*>(&Ks[0][kws[i]]) = *reinterpret_cast<const bf16x8*>(kgp[i]);
    *reinterpret_cast<bf16x8*>(&Vts[0][vws[i]]) = *reinterpret_cast<const bf16x8*>(vgp[i]);
  }
  __syncthreads();

  bf16x8 rk[3], rv[3];
  constexpr int NT = SEQ / 64;
  for (int kt = 0; kt < NT; ++kt) {
    const int cur = kt & 1;
    const bool pre = (kt < NT - 1);
    const bf16* ksb = Ks[cur];
    const bf16* vsb = Vts[cur];
    // issue next-tile global loads early
    if (pre) {
      const size_t koff = (size_t)(kt + 1) * 64 * HD;
      const size_t voff = (size_t)(kt + 1) * 64;
#pragma unroll
      for (int i = 0; i < 3; ++i) {
        rk[i] = *reinterpret_cast<const bf16x8*>(kgp[i] + koff);
        rv[i] = *reinterpret_cast<const bf16x8*>(vgp[i] + voff);
      }
    }

    // ---- S^T = K Q^T : sacc[g][kc] reg r -> S^T[ki=kc*16+l4*4+r][q0+g*16+l15]
    f32x4 sacc[2][4] = {};
    __builtin_amdgcn_s_setprio(1);
#pragma unroll
    for (int kc = 0; kc < 4; ++kc) {
      const int row = kc * 16 + l15;
#pragma unroll
      for (int kch = 0; kch < 3; ++kch) {
        const int slot = (kch * 4 + l4) ^ (l15 & 7);
        const bf16x8 kf = *reinterpret_cast<const bf16x8*>(&ksb[row * 128 + slot * 8]);
        sacc[0][kc] = __builtin_amdgcn_mfma_f32_16x16x32_bf16(kf, qf[0][kch], sacc[0][kc], 0, 0, 0);
        sacc[1][kc] = __builtin_amdgcn_mfma_f32_16x16x32_bf16(kf, qf[1][kch], sacc[1][kc], 0, 0, 0);
      }
    }
    __builtin_amdgcn_s_setprio(0);

    // ---- online softmax (exp2 domain), defer-max THR=8 ----
    float mx[2];
#pragma unroll
    for (int g = 0; g < 2; ++g) {
      float m = -1e30f;
#pragma unroll
      for (int kc = 0; kc < 4; ++kc)
#pragma unroll
        for (int r = 0; r < 4; ++r) m = fmaxf(m, sacc[g][kc][r]);
      m = fmaxf(m, __shfl_xor(m, 16, 64));
      m = fmaxf(m, __shfl_xor(m, 32, 64));
      mx[g] = m;
    }
    if (__any(fmaxf(mx[0] - mrun[0], mx[1] - mrun[1]) > 8.f)) {
#pragma unroll
      for (int g = 0; g < 2; ++g) {
        const float mnew = fmaxf(mrun[g], mx[g]);
        const float fac = exp2f(mrun[g] - mnew);
        mrun[g] = mnew;
        lrun[g] *= fac;
        float facr[4];
#pragma unroll
        for (int r = 0; r < 4; ++r) facr[r] = __shfl(fac, l4 * 4 + r, 64);
#pragma unroll
        for (int dc = 0; dc < 6; ++dc)
#pragma unroll
          for (int r = 0; r < 4; ++r) oacc[g][dc][r] *= facr[r];
      }
    }
    bf16x8 pf[2][2];
#pragma unroll
    for (int g = 0; g < 2; ++g) {
      float sum = 0.f;
#pragma unroll
      for (int kc = 0; kc < 4; ++kc)
#pragma unroll
        for (int r = 0; r < 4; ++r) {
          const float e = exp2f(sacc[g][kc][r] - mrun[g]);
          sacc[g][kc][r] = e;
          sum += e;
        }
      sum += __shfl_xor(sum, 16, 64);
      sum += __shfl_xor(sum, 32, 64);
      lrun[g] += sum;

      // transmute P (D-frag of S^T) -> PV A-frag, in-register
      unsigned int pk[4][2];
#pragma unroll
      for (int kc = 0; kc < 4; ++kc)
#pragma unroll
        for (int h = 0; h < 2; ++h) {
          unsigned int r_;
          asm("v_cvt_pk_bf16_f32 %0, %1, %2"
              : "=v"(r_) : "v"(sacc[g][kc][2 * h]), "v"(sacc[g][kc][2 * h + 1]));
          pk[kc][h] = r_;
        }
#pragma unroll
      for (int c = 0; c < 2; ++c) {
        unsigned int pd[4];
#pragma unroll
        for (int m = 0; m < 4; ++m) {
          const int sl = ((l4 & 1) * 2 + (m >> 1)) * 16 + l15;
          const unsigned int a = (unsigned int)__shfl((int)pk[c * 2][m & 1], sl, 64);
          const unsigned int b = (unsigned int)__shfl((int)pk[c * 2 + 1][m & 1], sl, 64);
          pd[m] = (l4 < 2) ? a : b;
        }
        pf[g][c] = *reinterpret_cast<bf16x8*>(pd);
      }
    }

    // ---- O += P * V ----
    __builtin_amdgcn_s_setprio(1);
#pragma unroll
    for (int c = 0; c < 2; ++c)
#pragma unroll
      for (int dc = 0; dc < 6; ++dc) {
        const int row = dc * 16 + l15;
        const int slot = (c * 4 + l4) ^ (l15 & 7);
        const bf16x8 vf = *reinterpret_cast<const bf16x8*>(&vsb[row * 64 + slot * 8]);
        oacc[0][dc] = __builtin_amdgcn_mfma_f32_16x16x32_bf16(pf[0][c], vf, oacc[0][dc], 0, 0, 0);
        oacc[1][dc] = __builtin_amdgcn_mfma_f32_16x16x32_bf16(pf[1][c], vf, oacc[1][dc], 0, 0, 0);
      }
    __builtin_amdgcn_s_setprio(0);

    // write next tile to the other buffer
    if (pre) {
#pragma unroll
      for (int i = 0; i < 3; ++i) {
        *reinterpret_cast<bf16x8*>(&Ks[cur ^ 1][kws[i]]) = rk[i];
        *reinterpret_cast<bf16x8*>(&Vts[cur ^ 1][vws[i]]) = rv[i];
      }
    }
    __syncthreads();
  }

  // ---- normalize + write ----
  const int b = bh >> 3, h = bh & 7;
#pragma unroll
  for (int g = 0; g < 2; ++g) {
    const float rlv = 1.f / lrun[g];
    float invr[4];
#pragma unroll
    for (int r = 0; r < 4; ++r) invr[r] = __shfl(rlv, l4 * 4 + r, 64);
#pragma unroll
    for (int r = 0; r < 4; ++r) {
      const int n = q0 + g * 16 + l4 * 4 + r;
#pragma unroll
      for (int dc = 0; dc < 6; ++dc) {
        const int d = dc * 16 + l15;
        o[((size_t)(b * SEQ + n)) * EMB + h * HD + d] = (bf16)(oacc[g][dc][r] * invr[r]);
      }
    }
  }
}

// ---------------- launch ----------------
extern "C" void kernel_launch(void* const* d_in, const int* in_sizes, int n_in,
                              void* d_out, int out_size, void* d_ws, size_t ws_size,
                              hipStream_t stream) {
  const float* x  = (const float*)d_in[0];
  const float* Wq = (const float*)d_in[1];
  const float* bq = (const float*)d_in[2];
  const float* Wk = (const float*)d_in[3];
  const float* bk = (const float*)d_in[4];
  const float* Wv = (const float*)d_in[5];
  const float* bv = (const float*)d_in[6];
  const float* Wo = (const float*)d_in[7];
  const float* bo = (const float*)d_in[8];

  const size_t XN = (size_t)MTOT * EMB;
  const size_t WN = (size_t)EMB * EMB;

  bf16* p = (bf16*)d_ws;
  bf16* xbf = p; p += XN;
  bf16* wqb = p; p += WN;
  bf16* wkb = p; p += WN;
  bf16* wvb = p; p += WN;
  bf16* wob = p; p += WN;
  bf16* qb  = p; p += XN;
  bf16* kb  = p; p += XN;
  bf16* vb  = p; p += XN;
  bf16* vtb = p; p += XN;
  bf16* ao  = p; p += XN;

  cast_f32_bf16<<<XN / 1024, 256, 0, stream>>>(x, xbf);
  cast_w4<<<dim3(WN / 1024, 4), 256, 0, stream>>>(Wq, Wk, Wv, Wo, wqb, wkb, wvb, wob);

  const dim3 gg(EMB / 128, MTOT / 128);
  gemm_bt<0><<<gg, 256, 0, stream>>>(xbf, wqb, bq, qb, QSCALE);  // scale folded into Q
  gemm_bt<0><<<gg, 256, 0, stream>>>(xbf, wkb, bk, kb, 1.f);
  gemm_bt<0><<<gg, 256, 0, stream>>>(xbf, wvb, bv, vb, 1.f);

  transpose_v<<<dim3(SEQ / 64, BHTOT), 256, 0, stream>>>(vb, vtb);
  attn_fwd<<<dim3(SEQ / 128, BHTOT), 256, 0, stream>>>(qb, kb, vtb, ao);

  gemm_bt<1><<<gg, 256, 0, stream>>>(ao, wob, bo, d_out, 1.f);
}

// Round 5
// 255.460 us; speedup vs baseline: 1.4716x; 1.0863x over previous
//
#include <hip/hip_runtime.h>

// MHA forward: x[2,4096,768] -> out[2,4096,768], 8 heads, head_dim 96.
// bf16 MFMA GEMMs (fp32 accum) + flash attention with 32x32 swapped-QK^T:
// lane-local softmax; P stays in D-frag order, V gathered to match (no
// cross-lane P movement at all).

typedef __bf16 bf16;
typedef __attribute__((ext_vector_type(4))) float f32x4;
typedef __attribute__((ext_vector_type(16))) float f32x16;
typedef __attribute__((ext_vector_type(8))) __bf16 bf16x8;
typedef __attribute__((ext_vector_type(4))) __bf16 bf16x4;
typedef __attribute__((ext_vector_type(4))) unsigned u32x4;

#define EMB 768
#define SEQ 4096
#define NB 2
#define NHEADS 8
#define HD 96
#define BHTOT (NB * NHEADS)     // 16
#define MTOT (NB * SEQ)         // 8192
// softmax scale folded into Q gemm epilogue, in exp2 domain:
#define QSCALE 0.14724241052735512f   // 96^-0.5 * log2(e)

// ---------------- fp32 -> bf16 cast (x) ----------------
__global__ __launch_bounds__(256) void cast_f32_bf16(const float* __restrict__ in,
                                                     bf16* __restrict__ out) {
  const int i = (blockIdx.x * 256 + threadIdx.x) * 4;
  const f32x4 v = *reinterpret_cast<const f32x4*>(in + i);
  bf16x4 o;
  o[0] = (bf16)v[0]; o[1] = (bf16)v[1]; o[2] = (bf16)v[2]; o[3] = (bf16)v[3];
  *reinterpret_cast<bf16x4*>(out + i) = o;
}

// ---------------- fused 4-weight cast ----------------
__global__ __launch_bounds__(256) void cast_w4(const float* __restrict__ w0,
                                               const float* __restrict__ w1,
                                               const float* __restrict__ w2,
                                               const float* __restrict__ w3,
                                               bf16* __restrict__ o0,
                                               bf16* __restrict__ o1,
                                               bf16* __restrict__ o2,
                                               bf16* __restrict__ o3) {
  const float* w = (blockIdx.y == 0) ? w0 : (blockIdx.y == 1) ? w1 : (blockIdx.y == 2) ? w2 : w3;
  bf16* o = (blockIdx.y == 0) ? o0 : (blockIdx.y == 1) ? o1 : (blockIdx.y == 2) ? o2 : o3;
  const int i = (blockIdx.x * 256 + threadIdx.x) * 4;
  const f32x4 v = *reinterpret_cast<const f32x4*>(w + i);
  bf16x4 ob;
  ob[0] = (bf16)v[0]; ob[1] = (bf16)v[1]; ob[2] = (bf16)v[2]; ob[3] = (bf16)v[3];
  *reinterpret_cast<bf16x4*>(o + i) = ob;
}

// ---------------- GEMM: C[M,768] = (A[M,768] * B[768,768]^T + bias)*oscale --
template <int MODE>
__global__ __launch_bounds__(256) void gemm_bt(const bf16* __restrict__ A,
                                               const bf16* __restrict__ B,
                                               const float* __restrict__ bias,
                                               void* __restrict__ out,
                                               float oscale) {
  constexpr int K = EMB;
  __shared__ bf16 As[128 * 32];
  __shared__ bf16 Bs[128 * 32];
  const int tid = threadIdx.x;
  const int lane = tid & 63;
  const int wid = tid >> 6;
  const int wr = wid >> 1, wc = wid & 1;
  const int l15 = lane & 15, l4 = lane >> 4;
  const int rowBase = blockIdx.y * 128;
  const int colBase = blockIdx.x * 128;

  f32x4 acc[4][4] = {};

  for (int kt = 0; kt < K / 32; ++kt) {
    const int kb = kt * 32;
#pragma unroll
    for (int i = 0; i < 2; ++i) {
      const int c = (wid * 2 + i) * 64 + lane;
      const int row = c >> 2, cc = c & 3;
      const bf16* ga = A + (size_t)(rowBase + row) * K + kb + cc * 8;
      const bf16* gb = B + (size_t)(colBase + row) * K + kb + cc * 8;
      __builtin_amdgcn_global_load_lds(
          (const __attribute__((address_space(1))) void*)ga,
          (__attribute__((address_space(3))) void*)(As + (size_t)(wid * 2 + i) * 512),
          16, 0, 0);
      __builtin_amdgcn_global_load_lds(
          (const __attribute__((address_space(1))) void*)gb,
          (__attribute__((address_space(3))) void*)(Bs + (size_t)(wid * 2 + i) * 512),
          16, 0, 0);
    }
    __syncthreads();
    bf16x8 af[4], bfr[4];
#pragma unroll
    for (int t = 0; t < 4; ++t) {
      af[t]  = *reinterpret_cast<const bf16x8*>(As + (wr * 64 + t * 16 + l15) * 32 + l4 * 8);
      bfr[t] = *reinterpret_cast<const bf16x8*>(Bs + (wc * 64 + t * 16 + l15) * 32 + l4 * 8);
    }
#pragma unroll
    for (int mt = 0; mt < 4; ++mt)
#pragma unroll
      for (int nt = 0; nt < 4; ++nt)
        acc[mt][nt] = __builtin_amdgcn_mfma_f32_16x16x32_bf16(af[mt], bfr[nt], acc[mt][nt], 0, 0, 0);
    __syncthreads();
  }

#pragma unroll
  for (int mt = 0; mt < 4; ++mt) {
#pragma unroll
    for (int nt = 0; nt < 4; ++nt) {
      const int gn = colBase + wc * 64 + nt * 16 + l15;
      const float bv = bias[gn];
#pragma unroll
      for (int r = 0; r < 4; ++r) {
        const int gm = rowBase + wr * 64 + mt * 16 + l4 * 4 + r;
        const float v = (acc[mt][nt][r] + bv) * oscale;
        if (MODE == 0) {
          const int b = gm >> 12, n = gm & (SEQ - 1);
          const int h = gn / HD, d = gn - h * HD;
          ((bf16*)out)[((size_t)(b * NHEADS + h) * SEQ + n) * HD + d] = (bf16)v;
        } else {
          ((float*)out)[(size_t)gm * EMB + gn] = v;
        }
      }
    }
  }
}

// ---------------- V transpose: [bh][n][96] -> [bh][96][n] ----------------
__global__ __launch_bounds__(256) void transpose_v(const bf16* __restrict__ v,
                                                   bf16* __restrict__ vt) {
  __shared__ bf16 T[96][72];
  const int bh = blockIdx.y;
  const int n0 = blockIdx.x * 64;
  const int tid = threadIdx.x;
#pragma unroll
  for (int i = 0; i < 3; ++i) {
    const int c = i * 256 + tid;
    const int n = c / 12, cc = c % 12;
    const bf16x8 val = *reinterpret_cast<const bf16x8*>(
        v + ((size_t)bh * SEQ + n0 + n) * HD + cc * 8);
#pragma unroll
    for (int j = 0; j < 8; ++j) T[cc * 8 + j][n] = val[j];
  }
  __syncthreads();
#pragma unroll
  for (int i = 0; i < 3; ++i) {
    const int c = i * 256 + tid;
    const int d = c >> 3, nc = c & 7;
    const bf16x8 val = *reinterpret_cast<const bf16x8*>(&T[d][nc * 8]);
    *reinterpret_cast<bf16x8*>(vt + ((size_t)bh * HD + d) * SEQ + n0 + nc * 8) = val;
  }
}

// ---------------- Flash attention (32x32 MFMA, lane-local softmax) --------
// Block = (bh, 128 q), 4 waves x 32 q, 256 threads. KV tile 64, dbuf LDS.
// S^T = mfma32(K, Q): lane holds q = lane&31; reg r -> ki = (r&3)+8(r>>2)+4lhi.
// Softmax lane-local (+__shfl_xor 32 for the half-exchange). P kept in D-frag
// order; V gathered with the SAME element->ki map -> PV needs no P shuffles.
__global__ __launch_bounds__(256, 2) void attn_fwd(const bf16* __restrict__ q,
                                                   const bf16* __restrict__ k,
                                                   const bf16* __restrict__ vt,
                                                   bf16* __restrict__ o) {
  __shared__ bf16 Ks[2][64 * 128];   // [ki][d] rows 256B, slot(16B) ^= row&7
  __shared__ bf16 Vts[2][96 * 64];   // [d][ki] rows 128B, slot ^= row&7
  const int tid = threadIdx.x;       // 0..255
  const int lane = tid & 63;
  const int wid = tid >> 6;          // 0..3
  const int l31 = lane & 31, lhi = lane >> 5;
  const int bh = blockIdx.y;
  const int q0 = blockIdx.x * 128 + wid * 32;
  const size_t head = (size_t)bh * SEQ * HD;
  const bf16* kg = k + head;
  const bf16* vg = vt + (size_t)bh * (size_t)HD * SEQ;

  // staging coords: 768 16B-chunks each for K (64x12) and Vt (96x8)
  int kws[3], vws[3];
  const bf16* kgp[3];
  const bf16* vgp[3];
  const int vc = tid & 7;
#pragma unroll
  for (int i = 0; i < 3; ++i) {
    const int c = i * 256 + tid;
    const int kr = c / 12, kcc = c % 12;
    kws[i] = kr * 128 + ((kcc ^ (kr & 7)) * 8);
    kgp[i] = kg + (size_t)kr * HD + kcc * 8;
    const int vr = i * 32 + (tid >> 3);
    vws[i] = vr * 64 + ((vc ^ (vr & 7)) * 8);
    vgp[i] = vg + (size_t)vr * SEQ + vc * 8;
  }

  // K A-frag byte-offsets (b128): K[kib*32+l31][dc*16 + lhi*8 + j]
  int krd[12];
#pragma unroll
  for (int kib = 0; kib < 2; ++kib)
#pragma unroll
    for (int dc = 0; dc < 6; ++dc) {
      const int row = kib * 32 + l31;
      krd[kib * 6 + dc] = (row * 128 + (((dc * 2 + lhi) ^ (l31 & 7)) * 8)) * 2;
    }
  // V A-frag byte-offsets (b64 pairs): element j <- Vt[db*32+l31]
  //   [kb*16 + (j&3) + 8*(j>>2) + 4*lhi]; second half = offset ^ 16.
  int vrd[12];
#pragma unroll
  for (int db = 0; db < 3; ++db)
#pragma unroll
    for (int kb = 0; kb < 4; ++kb) {
      const int row = db * 32 + l31;
      vrd[db * 4 + kb] = (row * 64 + (((kb * 2) ^ (l31 & 7)) * 8)) * 2 + lhi * 8;
    }

  // Q B-frag: lane holds Q[q0+l31][dc*16 + lhi*8 + j] (scale pre-folded)
  bf16x8 qf[6];
#pragma unroll
  for (int dc = 0; dc < 6; ++dc)
    qf[dc] = *reinterpret_cast<const bf16x8*>(
        q + head + (size_t)(q0 + l31) * HD + dc * 16 + lhi * 8);

  f32x16 oA = {}, oB = {}, oC = {};
  float mrun = -1e30f, lrun = 0.f;   // state for q = q0 + l31 (lane-local)

  // prologue: stage tile 0
#pragma unroll
  for (int i = 0; i < 3; ++i) {
    *reinterpret_cast<bf16x8*>(&Ks[0][kws[i]]) = *reinterpret_cast<const bf16x8*>(kgp[i]);
    *reinterpret_cast<bf16x8*>(&Vts[0][vws[i]]) = *reinterpret_cast<const bf16x8*>(vgp[i]);
  }
  __syncthreads();

  bf16x8 rk[3], rv[3];
  constexpr int NT = SEQ / 64;
  for (int kt = 0; kt < NT; ++kt) {
    const int cur = kt & 1;
    const bool pre = (kt < NT - 1);
    const char* ksb = (const char*)Ks[cur];
    const char* vsb = (const char*)Vts[cur];
    // issue next-tile global loads early (T14)
    if (pre) {
      const size_t koff = (size_t)(kt + 1) * 64 * HD;
      const size_t voff = (size_t)(kt + 1) * 64;
#pragma unroll
      for (int i = 0; i < 3; ++i) {
        rk[i] = *reinterpret_cast<const bf16x8*>(kgp[i] + koff);
        rv[i] = *reinterpret_cast<const bf16x8*>(vgp[i] + voff);
      }
    }

    // ---- S^T = K Q^T (two 32-ki blocks) ----
    f32x16 s0 = {}, s1 = {};
    __builtin_amdgcn_s_setprio(1);
#pragma unroll
    for (int dc = 0; dc < 6; ++dc) {
      const bf16x8 kf0 = *reinterpret_cast<const bf16x8*>(ksb + krd[dc]);
      const bf16x8 kf1 = *reinterpret_cast<const bf16x8*>(ksb + krd[6 + dc]);
      s0 = __builtin_amdgcn_mfma_f32_32x32x16_bf16(kf0, qf[dc], s0, 0, 0, 0);
      s1 = __builtin_amdgcn_mfma_f32_32x32x16_bf16(kf1, qf[dc], s1, 0, 0, 0);
    }
    __builtin_amdgcn_s_setprio(0);

    // ---- lane-local online softmax (exp2 domain, defer-max THR=8) ----
    float m0 = s0[0], m1 = s0[1], m2 = s0[2], m3 = s0[3];
#pragma unroll
    for (int i = 1; i < 4; ++i) {
      m0 = fmaxf(m0, s0[4 * i + 0]); m1 = fmaxf(m1, s0[4 * i + 1]);
      m2 = fmaxf(m2, s0[4 * i + 2]); m3 = fmaxf(m3, s0[4 * i + 3]);
    }
#pragma unroll
    for (int i = 0; i < 4; ++i) {
      m0 = fmaxf(m0, s1[4 * i + 0]); m1 = fmaxf(m1, s1[4 * i + 1]);
      m2 = fmaxf(m2, s1[4 * i + 2]); m3 = fmaxf(m3, s1[4 * i + 3]);
    }
    float mx = fmaxf(fmaxf(m0, m1), fmaxf(m2, m3));
    mx = fmaxf(mx, __shfl_xor(mx, 32, 64));   // both halves: max over 64 ki
    if (__any(mx - mrun > 8.f)) {
      const float mnew = fmaxf(mrun, mx);
      const float fac = exp2f(mrun - mnew);
      mrun = mnew;
      lrun *= fac;
#pragma unroll
      for (int i = 0; i < 16; ++i) { oA[i] *= fac; oB[i] *= fac; oC[i] *= fac; }
    }
    float a0 = 0.f, a1 = 0.f, a2 = 0.f, a3 = 0.f;
#pragma unroll
    for (int i = 0; i < 4; ++i) {
      s0[4 * i + 0] = exp2f(s0[4 * i + 0] - mrun); a0 += s0[4 * i + 0];
      s0[4 * i + 1] = exp2f(s0[4 * i + 1] - mrun); a1 += s0[4 * i + 1];
      s0[4 * i + 2] = exp2f(s0[4 * i + 2] - mrun); a2 += s0[4 * i + 2];
      s0[4 * i + 3] = exp2f(s0[4 * i + 3] - mrun); a3 += s0[4 * i + 3];
    }
#pragma unroll
    for (int i = 0; i < 4; ++i) {
      s1[4 * i + 0] = exp2f(s1[4 * i + 0] - mrun); a0 += s1[4 * i + 0];
      s1[4 * i + 1] = exp2f(s1[4 * i + 1] - mrun); a1 += s1[4 * i + 1];
      s1[4 * i + 2] = exp2f(s1[4 * i + 2] - mrun); a2 += s1[4 * i + 2];
      s1[4 * i + 3] = exp2f(s1[4 * i + 3] - mrun); a3 += s1[4 * i + 3];
    }
    float sum = (a0 + a1) + (a2 + a3);
    sum += __shfl_xor(sum, 32, 64);
    lrun += sum;

    // ---- P -> PV B-frags: pure lane-local cvt_pk (D-frag order kept) ----
    // pf[kb] element j holds P[q][kb*16 + (j&3) + 8*(j>>2) + 4*lhi].
    bf16x8 pf[4];
#pragma unroll
    for (int blk = 0; blk < 2; ++blk) {
      const f32x16& s = blk ? s1 : s0;
      unsigned c[8];
#pragma unroll
      for (int i = 0; i < 8; ++i)
        asm("v_cvt_pk_bf16_f32 %0, %1, %2"
            : "=v"(c[i]) : "v"(s[2 * i]), "v"(s[2 * i + 1]));
      const u32x4 wa = {c[0], c[1], c[2], c[3]};
      const u32x4 wb = {c[4], c[5], c[6], c[7]};
      pf[blk * 2 + 0] = __builtin_bit_cast(bf16x8, wa);
      pf[blk * 2 + 1] = __builtin_bit_cast(bf16x8, wb);
    }

    // ---- O^T += V^T P^T (V gathered to match P's ki map) ----
    __builtin_amdgcn_s_setprio(1);
#pragma unroll
    for (int kb = 0; kb < 4; ++kb) {
#pragma unroll
      for (int db = 0; db < 3; ++db) {
        const int off = vrd[db * 4 + kb];
        const bf16x4 vlo = *reinterpret_cast<const bf16x4*>(vsb + off);
        const bf16x4 vhi = *reinterpret_cast<const bf16x4*>(vsb + (off ^ 16));
        const bf16x8 vf = __builtin_shufflevector(vlo, vhi, 0, 1, 2, 3, 4, 5, 6, 7);
        if (db == 0) oA = __builtin_amdgcn_mfma_f32_32x32x16_bf16(vf, pf[kb], oA, 0, 0, 0);
        else if (db == 1) oB = __builtin_amdgcn_mfma_f32_32x32x16_bf16(vf, pf[kb], oB, 0, 0, 0);
        else oC = __builtin_amdgcn_mfma_f32_32x32x16_bf16(vf, pf[kb], oC, 0, 0, 0);
      }
    }
    __builtin_amdgcn_s_setprio(0);

    // write next tile to the other buffer
    if (pre) {
#pragma unroll
      for (int i = 0; i < 3; ++i) {
        *reinterpret_cast<bf16x8*>(&Ks[cur ^ 1][kws[i]]) = rk[i];
        *reinterpret_cast<bf16x8*>(&Vts[cur ^ 1][vws[i]]) = rv[i];
      }
    }
    __syncthreads();
  }

  // ---- normalize + write O^T -> o[m][768] (packed dword stores) ----
  const int b = bh >> 3, h = bh & 7;
  const int n = q0 + l31;
  bf16* obase = o + (size_t)(b * SEQ + n) * EMB + h * HD;
  const float inv = 1.f / lrun;
#pragma unroll
  for (int db = 0; db < 3; ++db) {
    const f32x16& ox = (db == 0) ? oA : (db == 1) ? oB : oC;
#pragma unroll
    for (int i = 0; i < 8; ++i) {
      const int r = 2 * i;
      const int d = db * 32 + (r & 3) + 8 * (r >> 2) + 4 * lhi;
      unsigned w;
      const float v0 = ox[r] * inv, v1 = ox[r + 1] * inv;
      asm("v_cvt_pk_bf16_f32 %0, %1, %2" : "=v"(w) : "v"(v0), "v"(v1));
      *reinterpret_cast<unsigned*>(obase + d) = w;
    }
  }
}

// ---------------- launch ----------------
extern "C" void kernel_launch(void* const* d_in, const int* in_sizes, int n_in,
                              void* d_out, int out_size, void* d_ws, size_t ws_size,
                              hipStream_t stream) {
  const float* x  = (const float*)d_in[0];
  const float* Wq = (const float*)d_in[1];
  const float* bq = (const float*)d_in[2];
  const float* Wk = (const float*)d_in[3];
  const float* bk = (const float*)d_in[4];
  const float* Wv = (const float*)d_in[5];
  const float* bv = (const float*)d_in[6];
  const float* Wo = (const float*)d_in[7];
  const float* bo = (const float*)d_in[8];

  const size_t XN = (size_t)MTOT * EMB;
  const size_t WN = (size_t)EMB * EMB;

  bf16* p = (bf16*)d_ws;
  bf16* xbf = p; p += XN;
  bf16* wqb = p; p += WN;
  bf16* wkb = p; p += WN;
  bf16* wvb = p; p += WN;
  bf16* wob = p; p += WN;
  bf16* qb  = p; p += XN;
  bf16* kb  = p; p += XN;
  bf16* vb  = p; p += XN;
  bf16* vtb = p; p += XN;
  bf16* ao  = p; p += XN;

  cast_f32_bf16<<<XN / 1024, 256, 0, stream>>>(x, xbf);
  cast_w4<<<dim3(WN / 1024, 4), 256, 0, stream>>>(Wq, Wk, Wv, Wo, wqb, wkb, wvb, wob);

  const dim3 gg(EMB / 128, MTOT / 128);
  gemm_bt<0><<<gg, 256, 0, stream>>>(xbf, wqb, bq, qb, QSCALE);  // scale folded into Q
  gemm_bt<0><<<gg, 256, 0, stream>>>(xbf, wkb, bk, kb, 1.f);
  gemm_bt<0><<<gg, 256, 0, stream>>>(xbf, wvb, bv, vb, 1.f);

  transpose_v<<<dim3(SEQ / 64, BHTOT), 256, 0, stream>>>(vb, vtb);
  attn_fwd<<<dim3(SEQ / 128, BHTOT), 256, 0, stream>>>(qb, kb, vtb, ao);

  gemm_bt<1><<<gg, 256, 0, stream>>>(ao, wob, bo, d_out, 1.f);
}